// Round 4
// baseline (170.426 us; speedup 1.0000x reference)
//
// RippleNet forward — R13: 3 dispatches (memset16B -> pairs -> attn).
//  - bin kernel DELETED: pairs block (j,r) self-compacts its 2048-entry mr
//    segment into an LDS list (LDS atomic counter; order irrelevant).
//  - finalize DELETED: kge/l2 via per-block LLC atomicAdd (fence-free,
//    device-scope atomics are LLC-coherent); attn waves atomicAdd bce +
//    done-counter (ordered by data-dep on atomic return); last wave
//    atomic-reads the 3 accumulators and writes the loss scalars.
//  - R2 lesson honored: NO __threadfence anywhere.
#include <hip/hip_runtime.h>
#include <math.h>

#define N_ENTITY 200000
#define N_REL 32
#define DIM 64
#define N_HOP 2
#define N_MEM 32
#define BATCH 1024
#define PAIR_PER_HOP (BATCH * N_MEM)       // 32768
#define N_PAIR (N_HOP * PAIR_PER_HOP)      // 65536
#define SEGS 32                            // mr segments (2048 pairs each)
#define SEG 2048
#define SEGCAP 192                         // per-(segment,relation) list cap
                                           // (binomial(2048,1/32): mean 64, sd 7.9 -> +16sd)
#define WPB 4                              // waves per block
#define TPAD 68                            // LDS transpose row pitch

typedef __attribute__((ext_vector_type(8))) short short8;   // 8 bf16 (A/B frag)
typedef __attribute__((ext_vector_type(4))) float floatx4;  // C/D frag

__device__ __forceinline__ float wave_reduce_sum(float v) {
    v += __shfl_xor(v, 1);
    v += __shfl_xor(v, 2);
    v += __shfl_xor(v, 4);
    v += __shfl_xor(v, 8);
    v += __shfl_xor(v, 16);
    v += __shfl_xor(v, 32);
    return v;
}

__device__ __forceinline__ unsigned short f2b(float x) {
    union { float f; unsigned u; } c; c.f = x;
    const unsigned r = (c.u + 0x7FFFu + ((c.u >> 16) & 1u)) >> 16;
    return (unsigned short)r;
}

__device__ __forceinline__ float b2f(short s) {
    union { unsigned u; float f; } c;
    c.u = ((unsigned)(unsigned short)s) << 16;
    return c.f;
}

__device__ __forceinline__ short8 pack8(const float4 a, const float4 b) {
    short8 s;
    s[0] = (short)f2b(a.x); s[1] = (short)f2b(a.y);
    s[2] = (short)f2b(a.z); s[3] = (short)f2b(a.w);
    s[4] = (short)f2b(b.x); s[5] = (short)f2b(b.y);
    s[6] = (short)f2b(b.z); s[7] = (short)f2b(b.w);
    return s;
}

__device__ __forceinline__ float sq4(const float4 a) {
    return a.x * a.x + a.y * a.y + a.z * a.z + a.w * a.w;
}

__device__ __forceinline__ float dot4(const float4 a, const float4 b) {
    return a.x * b.x + a.y * b.y + a.z * b.z + a.w * b.w;
}

// ---------------------------------------------------------------------------
// K1: MFMA gather-GEMM pairs kernel with in-block mr compaction.
// Grid (SEGS=32, N_REL=32): block (j,r) processes pairs of relation r inside
// mr segment [j*2048, (j+1)*2048).
// ---------------------------------------------------------------------------
__global__ __launch_bounds__(256) void ripple_pairs(
    const int* __restrict__ items,
    const int* __restrict__ mh,
    const int* __restrict__ mr,
    const int* __restrict__ mt,
    const float* __restrict__ item_table,
    const float* __restrict__ rel_table,
    float* __restrict__ wsL,            // [PAIR_PER_HOP] hop0 logits
    unsigned short* __restrict__ wsRh,  // [PAIR_PER_HOP][DIM] hop1 Rh (bf16)
    float* __restrict__ g_kge,
    float* __restrict__ g_l2)
{
    __shared__ __align__(16) float sTr[WPB][16 * TPAD];  // 17.4 KB transpose bufs
    __shared__ __align__(16) short8 sB[512];             // 8 KB packed bf16 R^T
    __shared__ float sRedR[WPB], sRedK[WPB], sRedL[WPB];
    __shared__ int slist[SEGCAP];
    __shared__ int sn;

    const int tid = (int)threadIdx.x;
    const int lane = tid & 63;
    const int w = tid >> 6;
    const int j = (int)blockIdx.x;
    const int r = (int)blockIdx.y;

    const int m16 = lane & 15;
    const int quad = lane >> 4;
    const int pbase = j * SEG;

    float* __restrict__ buf = &sTr[w][0];

    if (tid == 0) sn = 0;
    __syncthreads();

    // ---- compaction scan: 8 coalesced mr loads/thread; LDS-atomic append ----
    #pragma unroll
    for (int u = 0; u < 8; ++u) {
        const int idx = pbase + u * 256 + tid;
        if (mr[idx] == r) {
            const int pos = atomicAdd(&sn, 1);
            if (pos < SEGCAP) slist[pos] = idx;
        }
    }

    // ---- cooperative B staging (independent; overlaps the mr scan) ----
    {
        const float* __restrict__ Rb = rel_table + (size_t)r * (DIM * DIM);
        float rsq = 0.f;
        #pragma unroll
        for (int u = 0; u < 2; ++u) {
            const int slot = tid + 256 * u;
            const int s = slot >> 8;
            const int tn = (slot >> 6) & 3;
            const int ls = slot & 63;
            const float* src = Rb + (size_t)(16 * tn + (ls & 15)) * DIM
                             + 32 * s + 8 * (ls >> 4);
            const float4 a = *(const float4*)src;
            const float4 b = *(const float4*)(src + 4);
            rsq += sq4(a) + sq4(b);
            sB[slot] = pack8(a, b);
        }
        rsq = wave_reduce_sum(rsq);
        if (lane == 0) sRedR[w] = rsq;
    }
    __syncthreads();
    const float Rsum = sRedR[0] + sRedR[1] + sRedR[2] + sRedR[3];  // exact ||R||^2
    const int n = min(sn, SEGCAP);

    // ---- each wave's B fragments: 8 conflict-free ds_read_b128 ----
    short8 Bf[2][4];
    #pragma unroll
    for (int s = 0; s < 2; ++s)
        #pragma unroll
        for (int tn = 0; tn < 4; ++tn)
            Bf[s][tn] = sB[s * 256 + tn * 64 + lane];

    float kge = 0.f;
    float l2ht = 0.f;
    int cnt = 0;

    for (int tau = w; tau * 16 < n; tau += WPB) {
        const int base = tau * 16;
        const bool mvalid = (base + m16) < n;

        // ---- index chase from LDS list (short chain: LDS -> mh/mt -> rows) --
        const int p = slist[min(base + m16, n - 1)];
        const int hidx = mh[p];
        const int tidx = mt[p];
        const bool hop0 = p < PAIR_PER_HOP;   // block-uniform (segments don't
                                              // straddle the hop boundary)
        const int iidx = hop0 ? items[p >> 5] : 0;

        // ---- A rows + v0 row, all issued together ----
        const float* __restrict__ hp = item_table + (size_t)hidx * DIM + 8 * quad;
        const float* __restrict__ tp = item_table + (size_t)tidx * DIM + 8 * quad;
        const float4 h0a = *(const float4*)hp;
        const float4 h0b = *(const float4*)(hp + 4);
        const float4 h1a = *(const float4*)(hp + 32);
        const float4 h1b = *(const float4*)(hp + 36);
        const float4 t0a = *(const float4*)tp;
        const float4 t0b = *(const float4*)(tp + 4);
        const float4 t1a = *(const float4*)(tp + 32);
        const float4 t1b = *(const float4*)(tp + 36);

        float4 va0, va1, va2, va3;
        va0 = va1 = va2 = va3 = make_float4(0.f, 0.f, 0.f, 0.f);
        if (hop0) {
            const float* __restrict__ vp =
                item_table + (size_t)iidx * DIM + 16 * quad;
            va0 = *(const float4*)vp;
            va1 = *(const float4*)(vp + 4);
            va2 = *(const float4*)(vp + 8);
            va3 = *(const float4*)(vp + 12);
        }

        if (mvalid) {
            l2ht += sq4(h0a) + sq4(h0b) + sq4(h1a) + sq4(h1b)
                  + sq4(t0a) + sq4(t0b) + sq4(t1a) + sq4(t1b);
        }

        const short8 Ah0 = pack8(h0a, h0b);
        const short8 Ah1 = pack8(h1a, h1b);
        const short8 At0 = pack8(t0a, t0b);
        const short8 At1 = pack8(t1a, t1b);

        floatx4 Ch[4], Ct[4];
        const floatx4 z4 = {0.f, 0.f, 0.f, 0.f};
        #pragma unroll
        for (int tn = 0; tn < 4; ++tn) {
            Ch[tn] = __builtin_amdgcn_mfma_f32_16x16x32_bf16(Ah0, Bf[0][tn], z4, 0, 0, 0);
            Ch[tn] = __builtin_amdgcn_mfma_f32_16x16x32_bf16(Ah1, Bf[1][tn], Ch[tn], 0, 0, 0);
            Ct[tn] = __builtin_amdgcn_mfma_f32_16x16x32_bf16(At0, Bf[0][tn], z4, 0, 0, 0);
            Ct[tn] = __builtin_amdgcn_mfma_f32_16x16x32_bf16(At1, Bf[1][tn], Ct[tn], 0, 0, 0);
        }

        // ---- Ct transpose: C layout (row=4*quad+q, col=m16+16tn) -> rows ----
        #pragma unroll
        for (int tn = 0; tn < 4; ++tn) {
            const int col = m16 + 16 * tn;
            #pragma unroll
            for (int q = 0; q < 4; ++q)
                buf[(4 * quad + q) * TPAD + col] = Ct[tn][q];
        }
        const float* rowT = buf + m16 * TPAD;
        const float4 ct0 = *(const float4*)(rowT + 8 * quad);
        const float4 ct1 = *(const float4*)(rowT + 8 * quad + 4);
        const float4 ct2 = *(const float4*)(rowT + 32 + 8 * quad);
        const float4 ct3 = *(const float4*)(rowT + 32 + 8 * quad + 4);
        float hrt = dot4(h0a, ct0) + dot4(h0b, ct1) + dot4(h1a, ct2) + dot4(h1b, ct3);
        hrt += __shfl_xor(hrt, 16);
        hrt += __shfl_xor(hrt, 32);

        // ---- Ch transpose (same buffer; DS in-order per wave) ----
        #pragma unroll
        for (int tn = 0; tn < 4; ++tn) {
            const int col = m16 + 16 * tn;
            #pragma unroll
            for (int q = 0; q < 4; ++q)
                buf[(4 * quad + q) * TPAD + col] = Ch[tn][q];
        }
        const float* rowC = buf + m16 * TPAD;
        const float4 c0 = *(const float4*)(rowC + 16 * quad);
        const float4 c1 = *(const float4*)(rowC + 16 * quad + 4);
        const float4 c2 = *(const float4*)(rowC + 16 * quad + 8);
        const float4 c3 = *(const float4*)(rowC + 16 * quad + 12);

        // ---- hop0 logit: v0 regs . Ch ----
        float lg = dot4(va0, c0) + dot4(va1, c1) + dot4(va2, c2) + dot4(va3, c3);
        lg += __shfl_xor(lg, 16);
        lg += __shfl_xor(lg, 32);

        if (quad == 0 && mvalid) {
            kge += 1.f / (1.f + expf(-hrt));
            if (hop0) wsL[p] = lg;
        }

        // ---- hop1 Rh store: bf16, 2 x 16B ----
        if (mvalid && !hop0) {
            unsigned short* __restrict__ dst =
                wsRh + (size_t)(p - PAIR_PER_HOP) * DIM + 16 * quad;
            *(short8*)dst = pack8(c0, c1);
            *(short8*)(dst + 8) = pack8(c2, c3);
        }

        cnt += min(16, n - base);
    }

    // ---- block-reduce kge/l2, single LLC atomicAdd pair per block ----
    const float l2tot = wave_reduce_sum(l2ht) + (float)cnt * Rsum;
    const float kgetot = wave_reduce_sum(kge);
    if (lane == 0) { sRedK[w] = kgetot; sRedL[w] = l2tot; }
    __syncthreads();
    if (tid == 0) {
        atomicAdd(g_kge, sRedK[0] + sRedK[1] + sRedK[2] + sRedK[3]);
        atomicAdd(g_l2,  sRedL[0] + sRedL[1] + sRedL[2] + sRedL[3]);
    }
}

// ---------------------------------------------------------------------------
// K2: attention — one wave per batch element, zero barriers (R12 structure),
// plus fence-free last-wave loss finalize (R13).
// ---------------------------------------------------------------------------
__global__ __launch_bounds__(256) void ripple_attn(
    const int* __restrict__ items,
    const float* __restrict__ labels,
    const int* __restrict__ mt,
    const float* __restrict__ item_table,
    const float* __restrict__ W,
    const float* __restrict__ wsL,
    const unsigned short* __restrict__ wsRh,
    float* __restrict__ out,
    float* __restrict__ g_bce,
    float* __restrict__ g_kge,
    float* __restrict__ g_l2,
    int* __restrict__ g_done)
{
    __shared__ __align__(16) float sV[4][DIM];   // per-wave u / v vector

    const int tid = (int)threadIdx.x;
    const int lane = tid & 63;
    const int w = tid >> 6;
    const int b = (int)blockIdx.x * 4 + w;

    // ================= all global loads issued upfront =================
    const float v0 = item_table[(size_t)items[b] * DIM + lane];

    const float lab = labels[b];

    float l0 = (lane < N_MEM) ? wsL[b * N_MEM + lane] : -1e30f;

    // one mt index per lane: hop = lane>>5, m = lane&31
    const int myidx = mt[(lane >> 5) * PAIR_PER_HOP + b * N_MEM + (lane & 31)];

    // 64 t-row gathers (indices broadcast by shuffle; loads pipeline)
    float treg[64];
    #pragma unroll
    for (int m = 0; m < 64; ++m) {
        const int idx = __shfl(myidx, m);
        treg[m] = item_table[(size_t)idx * DIM + lane];
    }

    // hop1 Rh fragment: lane pair (2*m1, 2*m1+1) covers slot m1's 64 dims
    const int m1 = lane >> 1;
    const int d1 = (lane & 1) * 32;
    short8 rv[4];
    #pragma unroll
    for (int e = 0; e < 4; ++e)
        rv[e] = *(const short8*)(wsRh + (size_t)(b * N_MEM + m1) * DIM + d1 + 8 * e);

    const float4* __restrict__ Wrow = (const float4*)(W + (size_t)lane * DIM);

    // ================= hop 0 softmax (lanes 0..31 hold logits) =============
    float mx = l0;
    #pragma unroll
    for (int d = 16; d >= 1; d >>= 1) mx = fmaxf(mx, __shfl_xor(mx, d));
    const float e0 = expf(l0 - mx);
    float se = (lane < N_MEM) ? e0 : 0.f;
    #pragma unroll
    for (int d = 16; d >= 1; d >>= 1) se += __shfl_xor(se, d);
    const float pe0 = e0 / se;                  // valid in lanes 0..31

    float o0 = 0.f;
    #pragma unroll
    for (int m = 0; m < N_MEM; ++m)
        o0 = fmaf(treg[m], __shfl(pe0, m), o0);

    // ================= v1 = W (v0 + o0) =================
    sV[w][lane] = v0 + o0;                       // same-wave DS: in-order
    float v1;
    {
        float a0 = 0.f, a1 = 0.f, a2 = 0.f, a3 = 0.f;
        #pragma unroll
        for (int k = 0; k < 16; ++k) {
            const float4 w4 = Wrow[k];
            const float4 u4 = *(const float4*)&sV[w][k * 4];
            a0 = fmaf(w4.x, u4.x, a0);
            a1 = fmaf(w4.y, u4.y, a1);
            a2 = fmaf(w4.z, u4.z, a2);
            a3 = fmaf(w4.w, u4.w, a3);
        }
        v1 = (a0 + a1) + (a2 + a3);
    }

    // ================= hop 1 logits: a[m] = <Rh[m], v1> =================
    sV[w][lane] = v1;
    float dp = 0.f;
    #pragma unroll
    for (int e = 0; e < 4; ++e) {
        const float4 va = *(const float4*)&sV[w][d1 + 8 * e];
        const float4 vb = *(const float4*)&sV[w][d1 + 8 * e + 4];
        dp += b2f(rv[e][0]) * va.x + b2f(rv[e][1]) * va.y
            + b2f(rv[e][2]) * va.z + b2f(rv[e][3]) * va.w
            + b2f(rv[e][4]) * vb.x + b2f(rv[e][5]) * vb.y
            + b2f(rv[e][6]) * vb.z + b2f(rv[e][7]) * vb.w;
    }
    dp += __shfl_xor(dp, 1);                     // pair-sum: full 64-dim dot
    const float a1v = __shfl(dp, (lane & 31) * 2);  // lane m gets a[m]

    // ================= hop 1 softmax =================
    float av = (lane < N_MEM) ? a1v : -1e30f;
    mx = av;
    #pragma unroll
    for (int d = 16; d >= 1; d >>= 1) mx = fmaxf(mx, __shfl_xor(mx, d));
    const float e1 = expf(av - mx);
    se = (lane < N_MEM) ? e1 : 0.f;
    #pragma unroll
    for (int d = 16; d >= 1; d >>= 1) se += __shfl_xor(se, d);
    const float pe1 = e1 / se;                  // valid in lanes 0..31

    float o1 = 0.f;
    #pragma unroll
    for (int m = 0; m < N_MEM; ++m)
        o1 = fmaf(treg[N_MEM + m], __shfl(pe1, m), o1);

    // ================= epilogue: v2 = W (v1 + o1); score =================
    const float y = o0 + o1;
    sV[w][lane] = v1 + o1;
    float v2;
    {
        float a0 = 0.f, a1_ = 0.f, a2 = 0.f, a3 = 0.f;
        #pragma unroll
        for (int k = 0; k < 16; ++k) {
            const float4 w4 = Wrow[k];
            const float4 u4 = *(const float4*)&sV[w][k * 4];
            a0 = fmaf(w4.x, u4.x, a0);
            a1_ = fmaf(w4.y, u4.y, a1_);
            a2 = fmaf(w4.z, u4.z, a2);
            a3 = fmaf(w4.w, u4.w, a3);
        }
        v2 = (a0 + a1_) + (a2 + a3);
    }

    float s = wave_reduce_sum(v2 * y);
    s = 1.f / (1.f + expf(-s));
    if (lane == 0) {
        out[b] = s;
        const float logp = fmaxf(logf(s), -100.f);
        const float lognp = fmaxf(logf(1.f - s), -100.f);
        const float bval = lab * logp + (1.f - lab) * lognp;

        // ---- fence-free finalize protocol ----
        const float oldb = atomicAdd(g_bce, bval);
        asm volatile("" :: "v"(oldb));   // bce-add response received before
                                         // the done-increment issues
        const int oldd = atomicAdd(g_done, 1);
        if (oldd == BATCH - 1) {
            // all 1024 bce adds (and pairs' kge/l2 adds) complete at LLC;
            // read via atomic adds of 0 (coherent point, stale-L2 safe)
            const float bs = atomicAdd(g_bce, 0.0f);
            const float ks = atomicAdd(g_kge, 0.0f);
            const float ls = atomicAdd(g_l2, 0.0f);
            const float base_loss = -bs / (float)BATCH;
            const float kge_loss = -0.01f * (ks / (float)(BATCH * N_MEM));
            const float l2_loss = 1e-7f * ls;
            out[BATCH + 0] = base_loss + kge_loss + l2_loss;
            out[BATCH + 1] = base_loss;
            out[BATCH + 2] = kge_loss;
            out[BATCH + 3] = l2_loss;
        }
    }
}

extern "C" void kernel_launch(void* const* d_in, const int* in_sizes, int n_in,
                              void* d_out, int out_size, void* d_ws, size_t ws_size,
                              hipStream_t stream) {
    const int* items        = (const int*)d_in[0];
    const float* labels     = (const float*)d_in[1];
    const int* mh           = (const int*)d_in[2];
    const int* mr           = (const int*)d_in[3];
    const int* mt           = (const int*)d_in[4];
    const float* item_table = (const float*)d_in[5];
    const float* rel_table  = (const float*)d_in[6];
    const float* W          = (const float*)d_in[7];
    float* out = (float*)d_out;

    // workspace: wsL[32768] f32 | wsRh[32768*64] bf16 (4.2MB) |
    //            g_done int | g_bce | g_kge | g_l2  (16B, memset-zeroed)
    float* ws = (float*)d_ws;
    float* wsL            = ws;
    unsigned short* wsRh  = (unsigned short*)(wsL + PAIR_PER_HOP);
    int*   g_done         = (int*)(wsRh + (size_t)PAIR_PER_HOP * DIM);
    float* g_bce          = (float*)(g_done + 1);
    float* g_kge          = g_bce + 1;
    float* g_l2           = g_kge + 1;

    hipMemsetAsync(g_done, 0, 16, stream);
    dim3 gpairs(SEGS, N_REL);
    ripple_pairs<<<gpairs, 256, 0, stream>>>(items, mh, mr, mt, item_table,
                                             rel_table, wsL, wsRh, g_kge, g_l2);
    ripple_attn<<<BATCH / 4, 256, 0, stream>>>(items, labels, mt, item_table, W,
                                               wsL, wsRh, out,
                                               g_bce, g_kge, g_l2, g_done);
}

// Round 5
// 128.529 us; speedup vs baseline: 1.3260x; 1.3260x over previous
//
// RippleNet forward — R14: 3 dispatches (pairs -> attn -> finalize), ZERO
// global atomics, ZERO memsets, ZERO fences.
//  - R4 post-mortem: 1000-way same-cacheline atomicAdd fan-in costs ~30-40us
//    serialized at the LLC -> finalize reverted to plain stores + 1-block
//    reduction kernel (R3-proven). R2 lesson: no __threadfence.
//  - KEPT from R4: in-block mr compaction in pairs (deletes memset + bin
//    dispatches; LDS-only counter; passed absmax 0.0 in R4).
//  - attn: R3-proven wave-per-batch-element, zero barriers.
#include <hip/hip_runtime.h>
#include <math.h>

#define N_ENTITY 200000
#define N_REL 32
#define DIM 64
#define N_HOP 2
#define N_MEM 32
#define BATCH 1024
#define PAIR_PER_HOP (BATCH * N_MEM)       // 32768
#define N_PAIR (N_HOP * PAIR_PER_HOP)      // 65536
#define SEGS 32                            // mr segments (2048 pairs each)
#define SEG 2048
#define SEGCAP 192                         // per-(segment,relation) cap
                                           // (binomial(2048,1/32): mean 64, sd 7.9 -> +16sd)
#define WPB 4                              // waves per block
#define NBLK_RED (SEGS * N_REL)            // 1024 per-block reduction slots
#define TPAD 68                            // LDS transpose row pitch

typedef __attribute__((ext_vector_type(8))) short short8;   // 8 bf16 (A/B frag)
typedef __attribute__((ext_vector_type(4))) float floatx4;  // C/D frag

__device__ __forceinline__ float wave_reduce_sum(float v) {
    v += __shfl_xor(v, 1);
    v += __shfl_xor(v, 2);
    v += __shfl_xor(v, 4);
    v += __shfl_xor(v, 8);
    v += __shfl_xor(v, 16);
    v += __shfl_xor(v, 32);
    return v;
}

__device__ __forceinline__ unsigned short f2b(float x) {
    union { float f; unsigned u; } c; c.f = x;
    const unsigned r = (c.u + 0x7FFFu + ((c.u >> 16) & 1u)) >> 16;
    return (unsigned short)r;
}

__device__ __forceinline__ float b2f(short s) {
    union { unsigned u; float f; } c;
    c.u = ((unsigned)(unsigned short)s) << 16;
    return c.f;
}

__device__ __forceinline__ short8 pack8(const float4 a, const float4 b) {
    short8 s;
    s[0] = (short)f2b(a.x); s[1] = (short)f2b(a.y);
    s[2] = (short)f2b(a.z); s[3] = (short)f2b(a.w);
    s[4] = (short)f2b(b.x); s[5] = (short)f2b(b.y);
    s[6] = (short)f2b(b.z); s[7] = (short)f2b(b.w);
    return s;
}

__device__ __forceinline__ float sq4(const float4 a) {
    return a.x * a.x + a.y * a.y + a.z * a.z + a.w * a.w;
}

__device__ __forceinline__ float dot4(const float4 a, const float4 b) {
    return a.x * b.x + a.y * b.y + a.z * b.z + a.w * b.w;
}

// ---------------------------------------------------------------------------
// K1: MFMA gather-GEMM pairs kernel with in-block mr compaction.
// Grid (SEGS=32, N_REL=32): block (j,r) handles relation r within mr segment
// [j*2048,(j+1)*2048). No global counters; reductions -> per-block ws slots.
// ---------------------------------------------------------------------------
__global__ __launch_bounds__(256) void ripple_pairs(
    const int* __restrict__ items,
    const int* __restrict__ mh,
    const int* __restrict__ mr,
    const int* __restrict__ mt,
    const float* __restrict__ item_table,
    const float* __restrict__ rel_table,
    float* __restrict__ wsL,            // [PAIR_PER_HOP] hop0 logits
    unsigned short* __restrict__ wsRh,  // [PAIR_PER_HOP][DIM] hop1 Rh (bf16)
    float* __restrict__ ws_kge,         // [NBLK_RED]
    float* __restrict__ ws_l2)          // [NBLK_RED]
{
    __shared__ __align__(16) float sTr[WPB][16 * TPAD];  // 17.4 KB transpose bufs
    __shared__ __align__(16) short8 sB[512];             // 8 KB packed bf16 R^T
    __shared__ float sRedR[WPB], sRedK[WPB], sRedL[WPB];
    __shared__ int slist[SEGCAP];
    __shared__ int sn;

    const int tid = (int)threadIdx.x;
    const int lane = tid & 63;
    const int w = tid >> 6;
    const int j = (int)blockIdx.x;
    const int r = (int)blockIdx.y;

    const int m16 = lane & 15;
    const int quad = lane >> 4;
    const int pbase = j * SEG;

    float* __restrict__ buf = &sTr[w][0];

    if (tid == 0) sn = 0;
    __syncthreads();

    // ---- compaction scan: 8 coalesced mr loads/thread; LDS-atomic append ----
    #pragma unroll
    for (int u = 0; u < 8; ++u) {
        const int idx = pbase + u * 256 + tid;
        if (mr[idx] == r) {
            const int pos = atomicAdd(&sn, 1);
            if (pos < SEGCAP) slist[pos] = idx;
        }
    }

    // ---- cooperative B staging (independent; overlaps the mr scan) ----
    {
        const float* __restrict__ Rb = rel_table + (size_t)r * (DIM * DIM);
        float rsq = 0.f;
        #pragma unroll
        for (int u = 0; u < 2; ++u) {
            const int slot = tid + 256 * u;
            const int s = slot >> 8;
            const int tn = (slot >> 6) & 3;
            const int ls = slot & 63;
            const float* src = Rb + (size_t)(16 * tn + (ls & 15)) * DIM
                             + 32 * s + 8 * (ls >> 4);
            const float4 a = *(const float4*)src;
            const float4 b = *(const float4*)(src + 4);
            rsq += sq4(a) + sq4(b);
            sB[slot] = pack8(a, b);
        }
        rsq = wave_reduce_sum(rsq);
        if (lane == 0) sRedR[w] = rsq;
    }
    __syncthreads();
    const float Rsum = sRedR[0] + sRedR[1] + sRedR[2] + sRedR[3];  // exact ||R||^2
    const int n = min(sn, SEGCAP);

    // ---- each wave's B fragments: 8 conflict-free ds_read_b128 ----
    short8 Bf[2][4];
    #pragma unroll
    for (int s = 0; s < 2; ++s)
        #pragma unroll
        for (int tn = 0; tn < 4; ++tn)
            Bf[s][tn] = sB[s * 256 + tn * 64 + lane];

    float kge = 0.f;
    float l2ht = 0.f;
    int cnt = 0;

    for (int tau = w; tau * 16 < n; tau += WPB) {
        const int base = tau * 16;
        const bool mvalid = (base + m16) < n;

        // ---- index chase from LDS list (short chain: LDS -> mh/mt -> rows) --
        const int p = slist[min(base + m16, n - 1)];
        const int hidx = mh[p];
        const int tidx = mt[p];
        const bool hop0 = p < PAIR_PER_HOP;   // block-uniform (segments don't
                                              // straddle the hop boundary)
        const int iidx = hop0 ? items[p >> 5] : 0;

        // ---- A rows + v0 row, all issued together ----
        const float* __restrict__ hp = item_table + (size_t)hidx * DIM + 8 * quad;
        const float* __restrict__ tp = item_table + (size_t)tidx * DIM + 8 * quad;
        const float4 h0a = *(const float4*)hp;
        const float4 h0b = *(const float4*)(hp + 4);
        const float4 h1a = *(const float4*)(hp + 32);
        const float4 h1b = *(const float4*)(hp + 36);
        const float4 t0a = *(const float4*)tp;
        const float4 t0b = *(const float4*)(tp + 4);
        const float4 t1a = *(const float4*)(tp + 32);
        const float4 t1b = *(const float4*)(tp + 36);

        float4 va0, va1, va2, va3;
        va0 = va1 = va2 = va3 = make_float4(0.f, 0.f, 0.f, 0.f);
        if (hop0) {
            const float* __restrict__ vp =
                item_table + (size_t)iidx * DIM + 16 * quad;
            va0 = *(const float4*)vp;
            va1 = *(const float4*)(vp + 4);
            va2 = *(const float4*)(vp + 8);
            va3 = *(const float4*)(vp + 12);
        }

        if (mvalid) {
            l2ht += sq4(h0a) + sq4(h0b) + sq4(h1a) + sq4(h1b)
                  + sq4(t0a) + sq4(t0b) + sq4(t1a) + sq4(t1b);
        }

        const short8 Ah0 = pack8(h0a, h0b);
        const short8 Ah1 = pack8(h1a, h1b);
        const short8 At0 = pack8(t0a, t0b);
        const short8 At1 = pack8(t1a, t1b);

        floatx4 Ch[4], Ct[4];
        const floatx4 z4 = {0.f, 0.f, 0.f, 0.f};
        #pragma unroll
        for (int tn = 0; tn < 4; ++tn) {
            Ch[tn] = __builtin_amdgcn_mfma_f32_16x16x32_bf16(Ah0, Bf[0][tn], z4, 0, 0, 0);
            Ch[tn] = __builtin_amdgcn_mfma_f32_16x16x32_bf16(Ah1, Bf[1][tn], Ch[tn], 0, 0, 0);
            Ct[tn] = __builtin_amdgcn_mfma_f32_16x16x32_bf16(At0, Bf[0][tn], z4, 0, 0, 0);
            Ct[tn] = __builtin_amdgcn_mfma_f32_16x16x32_bf16(At1, Bf[1][tn], Ct[tn], 0, 0, 0);
        }

        // ---- Ct transpose: C layout (row=4*quad+q, col=m16+16tn) -> rows ----
        #pragma unroll
        for (int tn = 0; tn < 4; ++tn) {
            const int col = m16 + 16 * tn;
            #pragma unroll
            for (int q = 0; q < 4; ++q)
                buf[(4 * quad + q) * TPAD + col] = Ct[tn][q];
        }
        const float* rowT = buf + m16 * TPAD;
        const float4 ct0 = *(const float4*)(rowT + 8 * quad);
        const float4 ct1 = *(const float4*)(rowT + 8 * quad + 4);
        const float4 ct2 = *(const float4*)(rowT + 32 + 8 * quad);
        const float4 ct3 = *(const float4*)(rowT + 32 + 8 * quad + 4);
        float hrt = dot4(h0a, ct0) + dot4(h0b, ct1) + dot4(h1a, ct2) + dot4(h1b, ct3);
        hrt += __shfl_xor(hrt, 16);
        hrt += __shfl_xor(hrt, 32);

        // ---- Ch transpose (same buffer; DS in-order per wave) ----
        #pragma unroll
        for (int tn = 0; tn < 4; ++tn) {
            const int col = m16 + 16 * tn;
            #pragma unroll
            for (int q = 0; q < 4; ++q)
                buf[(4 * quad + q) * TPAD + col] = Ch[tn][q];
        }
        const float* rowC = buf + m16 * TPAD;
        const float4 c0 = *(const float4*)(rowC + 16 * quad);
        const float4 c1 = *(const float4*)(rowC + 16 * quad + 4);
        const float4 c2 = *(const float4*)(rowC + 16 * quad + 8);
        const float4 c3 = *(const float4*)(rowC + 16 * quad + 12);

        // ---- hop0 logit: v0 regs . Ch ----
        float lg = dot4(va0, c0) + dot4(va1, c1) + dot4(va2, c2) + dot4(va3, c3);
        lg += __shfl_xor(lg, 16);
        lg += __shfl_xor(lg, 32);

        if (quad == 0 && mvalid) {
            kge += 1.f / (1.f + expf(-hrt));
            if (hop0) wsL[p] = lg;
        }

        // ---- hop1 Rh store: bf16, 2 x 16B ----
        if (mvalid && !hop0) {
            unsigned short* __restrict__ dst =
                wsRh + (size_t)(p - PAIR_PER_HOP) * DIM + 16 * quad;
            *(short8*)dst = pack8(c0, c1);
            *(short8*)(dst + 8) = pack8(c2, c3);
        }

        cnt += min(16, n - base);
    }

    // ---- block-reduce kge/l2 -> per-block workspace slot (no atomics) ----
    const float l2tot = wave_reduce_sum(l2ht) + (float)cnt * Rsum;
    const float kgetot = wave_reduce_sum(kge);
    if (lane == 0) { sRedK[w] = kgetot; sRedL[w] = l2tot; }
    __syncthreads();
    if (tid == 0) {
        const int slot = r * SEGS + j;
        ws_kge[slot] = sRedK[0] + sRedK[1] + sRedK[2] + sRedK[3];
        ws_l2[slot]  = sRedL[0] + sRedL[1] + sRedL[2] + sRedL[3];
    }
}

// ---------------------------------------------------------------------------
// K2: attention — one wave per batch element, zero barriers (R3-proven).
// ---------------------------------------------------------------------------
__global__ __launch_bounds__(256) void ripple_attn(
    const int* __restrict__ items,
    const float* __restrict__ labels,
    const int* __restrict__ mt,
    const float* __restrict__ item_table,
    const float* __restrict__ W,
    const float* __restrict__ wsL,
    const unsigned short* __restrict__ wsRh,
    float* __restrict__ out,
    float* __restrict__ ws_bce)
{
    __shared__ __align__(16) float sV[4][DIM];   // per-wave u / v vector

    const int tid = (int)threadIdx.x;
    const int lane = tid & 63;
    const int w = tid >> 6;
    const int b = (int)blockIdx.x * 4 + w;

    // ================= all global loads issued upfront =================
    const float v0 = item_table[(size_t)items[b] * DIM + lane];

    const float lab = labels[b];

    float l0 = (lane < N_MEM) ? wsL[b * N_MEM + lane] : -1e30f;

    // one mt index per lane: hop = lane>>5, m = lane&31
    const int myidx = mt[(lane >> 5) * PAIR_PER_HOP + b * N_MEM + (lane & 31)];

    // 64 t-row gathers (indices broadcast by shuffle; loads pipeline)
    float treg[64];
    #pragma unroll
    for (int m = 0; m < 64; ++m) {
        const int idx = __shfl(myidx, m);
        treg[m] = item_table[(size_t)idx * DIM + lane];
    }

    // hop1 Rh fragment: lane pair (2*m1, 2*m1+1) covers slot m1's 64 dims
    const int m1 = lane >> 1;
    const int d1 = (lane & 1) * 32;
    short8 rv[4];
    #pragma unroll
    for (int e = 0; e < 4; ++e)
        rv[e] = *(const short8*)(wsRh + (size_t)(b * N_MEM + m1) * DIM + d1 + 8 * e);

    const float4* __restrict__ Wrow = (const float4*)(W + (size_t)lane * DIM);

    // ================= hop 0 softmax (lanes 0..31 hold logits) =============
    float mx = l0;
    #pragma unroll
    for (int d = 16; d >= 1; d >>= 1) mx = fmaxf(mx, __shfl_xor(mx, d));
    const float e0 = expf(l0 - mx);
    float se = (lane < N_MEM) ? e0 : 0.f;
    #pragma unroll
    for (int d = 16; d >= 1; d >>= 1) se += __shfl_xor(se, d);
    const float pe0 = e0 / se;                  // valid in lanes 0..31

    float o0 = 0.f;
    #pragma unroll
    for (int m = 0; m < N_MEM; ++m)
        o0 = fmaf(treg[m], __shfl(pe0, m), o0);

    // ================= v1 = W (v0 + o0) =================
    sV[w][lane] = v0 + o0;                       // same-wave DS: in-order
    float v1;
    {
        float a0 = 0.f, a1 = 0.f, a2 = 0.f, a3 = 0.f;
        #pragma unroll
        for (int k = 0; k < 16; ++k) {
            const float4 w4 = Wrow[k];
            const float4 u4 = *(const float4*)&sV[w][k * 4];
            a0 = fmaf(w4.x, u4.x, a0);
            a1 = fmaf(w4.y, u4.y, a1);
            a2 = fmaf(w4.z, u4.z, a2);
            a3 = fmaf(w4.w, u4.w, a3);
        }
        v1 = (a0 + a1) + (a2 + a3);
    }

    // ================= hop 1 logits: a[m] = <Rh[m], v1> =================
    sV[w][lane] = v1;
    float dp = 0.f;
    #pragma unroll
    for (int e = 0; e < 4; ++e) {
        const float4 va = *(const float4*)&sV[w][d1 + 8 * e];
        const float4 vb = *(const float4*)&sV[w][d1 + 8 * e + 4];
        dp += b2f(rv[e][0]) * va.x + b2f(rv[e][1]) * va.y
            + b2f(rv[e][2]) * va.z + b2f(rv[e][3]) * va.w
            + b2f(rv[e][4]) * vb.x + b2f(rv[e][5]) * vb.y
            + b2f(rv[e][6]) * vb.z + b2f(rv[e][7]) * vb.w;
    }
    dp += __shfl_xor(dp, 1);                     // pair-sum: full 64-dim dot
    const float a1v = __shfl(dp, (lane & 31) * 2);  // lane m gets a[m]

    // ================= hop 1 softmax =================
    float av = (lane < N_MEM) ? a1v : -1e30f;
    mx = av;
    #pragma unroll
    for (int d = 16; d >= 1; d >>= 1) mx = fmaxf(mx, __shfl_xor(mx, d));
    const float e1 = expf(av - mx);
    se = (lane < N_MEM) ? e1 : 0.f;
    #pragma unroll
    for (int d = 16; d >= 1; d >>= 1) se += __shfl_xor(se, d);
    const float pe1 = e1 / se;                  // valid in lanes 0..31

    float o1 = 0.f;
    #pragma unroll
    for (int m = 0; m < N_MEM; ++m)
        o1 = fmaf(treg[N_MEM + m], __shfl(pe1, m), o1);

    // ================= epilogue: v2 = W (v1 + o1); score =================
    const float y = o0 + o1;
    sV[w][lane] = v1 + o1;
    float v2;
    {
        float a0 = 0.f, a1_ = 0.f, a2 = 0.f, a3 = 0.f;
        #pragma unroll
        for (int k = 0; k < 16; ++k) {
            const float4 w4 = Wrow[k];
            const float4 u4 = *(const float4*)&sV[w][k * 4];
            a0 = fmaf(w4.x, u4.x, a0);
            a1_ = fmaf(w4.y, u4.y, a1_);
            a2 = fmaf(w4.z, u4.z, a2);
            a3 = fmaf(w4.w, u4.w, a3);
        }
        v2 = (a0 + a1_) + (a2 + a3);
    }

    float s = wave_reduce_sum(v2 * y);
    s = 1.f / (1.f + expf(-s));
    if (lane == 0) {
        out[b] = s;
        const float logp = fmaxf(logf(s), -100.f);
        const float lognp = fmaxf(logf(1.f - s), -100.f);
        ws_bce[b] = lab * logp + (1.f - lab) * lognp;
    }
}

// ---------------------------------------------------------------------------
// K3: loss finalize (1 block).
// ---------------------------------------------------------------------------
__global__ __launch_bounds__(256) void ripple_finalize(
    const float* __restrict__ ws_bce,
    const float* __restrict__ ws_kge,
    const float* __restrict__ ws_l2,
    float* __restrict__ out)
{
    __shared__ float sb[4], sk[4], sl[4];
    const int tid = (int)threadIdx.x;
    float bsum = 0.f, ksum = 0.f, lsum = 0.f;
    for (int i = tid; i < BATCH; i += 256) bsum += ws_bce[i];
    for (int i = tid; i < NBLK_RED; i += 256) {
        ksum += ws_kge[i];
        lsum += ws_l2[i];
    }
    bsum = wave_reduce_sum(bsum);
    ksum = wave_reduce_sum(ksum);
    lsum = wave_reduce_sum(lsum);
    const int w = tid >> 6;
    if ((tid & 63) == 0) { sb[w] = bsum; sk[w] = ksum; sl[w] = lsum; }
    __syncthreads();
    if (tid == 0) {
        const float bs = sb[0] + sb[1] + sb[2] + sb[3];
        const float ks = sk[0] + sk[1] + sk[2] + sk[3];
        const float ls = sl[0] + sl[1] + sl[2] + sl[3];
        const float base_loss = -bs / (float)BATCH;
        const float kge_loss = -0.01f * (ks / (float)(BATCH * N_MEM));
        const float l2_loss = 1e-7f * ls;
        out[BATCH + 0] = base_loss + kge_loss + l2_loss;
        out[BATCH + 1] = base_loss;
        out[BATCH + 2] = kge_loss;
        out[BATCH + 3] = l2_loss;
    }
}

extern "C" void kernel_launch(void* const* d_in, const int* in_sizes, int n_in,
                              void* d_out, int out_size, void* d_ws, size_t ws_size,
                              hipStream_t stream) {
    const int* items        = (const int*)d_in[0];
    const float* labels     = (const float*)d_in[1];
    const int* mh           = (const int*)d_in[2];
    const int* mr           = (const int*)d_in[3];
    const int* mt           = (const int*)d_in[4];
    const float* item_table = (const float*)d_in[5];
    const float* rel_table  = (const float*)d_in[6];
    const float* W          = (const float*)d_in[7];
    float* out = (float*)d_out;

    // workspace: wsL[32768] f32 | wsRh[32768*64] bf16 (4.2MB) |
    //            ws_bce[BATCH] | ws_kge[NBLK_RED] | ws_l2[NBLK_RED]
    float* ws = (float*)d_ws;
    float* wsL            = ws;
    unsigned short* wsRh  = (unsigned short*)(wsL + PAIR_PER_HOP);
    float* ws_bce         = (float*)(wsRh + (size_t)PAIR_PER_HOP * DIM);
    float* ws_kge         = ws_bce + BATCH;
    float* ws_l2          = ws_kge + NBLK_RED;

    dim3 gpairs(SEGS, N_REL);
    ripple_pairs<<<gpairs, 256, 0, stream>>>(items, mh, mr, mt, item_table,
                                             rel_table, wsL, wsRh, ws_kge, ws_l2);
    ripple_attn<<<BATCH / 4, 256, 0, stream>>>(items, labels, mt, item_table, W,
                                               wsL, wsRh, out, ws_bce);
    ripple_finalize<<<1, 256, 0, stream>>>(ws_bce, ws_kge, ws_l2, out);
}